// Round 5
// baseline (611.934 us; speedup 1.0000x reference)
//
#include <hip/hip_runtime.h>
#include <hip/hip_bf16.h>

// BasicBlock sparse conv v5: output-centric gather conv, bf16 MFMA.
// vs v4: (1) neighbor indices staged in LDS pre-loop (one barrier) -> in-loop
// idx reads are ds_read (lgkmcnt domain), out of the in-order vmcnt chain.
// (2) deeper vmem rings: A depth 5 (prefetch k+4), B depth 3 (prefetch k+2).
// Issue order per iter: ds-idx(k+6) | B(k+2) | A(k+4) | fence | MFMA(k) | fence.
// Worst in-order coupling now lat_gather/3.

#define N_VOX 200000
#define NP 200064            // padded rows: 1563 blocks * 128 rows
#define P_PAIR 65536
#define EPS_BN 1e-5f

typedef __attribute__((ext_vector_type(8))) short bf16x8;   // 8 bf16 = 4 VGPRs
typedef __attribute__((ext_vector_type(4))) float f32x4;

// ---------------- prep kernels ----------------

__global__ void fill_kernel(int* __restrict__ nbrT, float* __restrict__ sums) {
    int p = blockIdx.y;                                   // plane 0..26
    long i = ((long)blockIdx.x * 256 + threadIdx.x) * 4;  // element in plane
    if (i < NP) {
        int4 v;
        if (p == 13) {   // identity plane (center tap); pad rows -> zero row
            v.x = (i + 0 < N_VOX) ? (int)i + 0 : N_VOX;
            v.y = (i + 1 < N_VOX) ? (int)i + 1 : N_VOX;
            v.z = (i + 2 < N_VOX) ? (int)i + 2 : N_VOX;
            v.w = (i + 3 < N_VOX) ? (int)i + 3 : N_VOX;
        } else {
            v.x = v.y = v.z = v.w = N_VOX;                // sentinel -> zero row
        }
        *(int4*)(nbrT + (long)p * NP + i) = v;
    }
    if (p == 0 && blockIdx.x == 0 && threadIdx.x < 64) {  // zero sums[256]
        float4 z = {0.f, 0.f, 0.f, 0.f};
        ((float4*)sums)[threadIdx.x] = z;
    }
}

__global__ void scatter_kernel(const int* __restrict__ out_maps,
                               const int* __restrict__ in_maps,
                               int* __restrict__ nbrT) {
    int idx = blockIdx.x * 256 + threadIdx.x;       // < 26*65536
    int o = out_maps[idx];
    if (o < N_VOX) {
        int k = idx >> 16;                          // offset index 0..25
        int p = k + (k >= 13);                      // weight plane (skip center)
        nbrT[(long)p * NP + o] = in_maps[idx];
    }
}

__global__ void cast_x_kernel(const float* __restrict__ x,
                              __hip_bfloat16* __restrict__ xb) {
    long i = ((long)blockIdx.x * 256 + threadIdx.x) * 4;
    if (i >= (long)(N_VOX + 1) * 64) return;
    __hip_bfloat16 t[4];
    if (i < (long)N_VOX * 64) {
        float4 v = *(const float4*)(x + i);
        t[0] = __float2bfloat16(v.x); t[1] = __float2bfloat16(v.y);
        t[2] = __float2bfloat16(v.z); t[3] = __float2bfloat16(v.w);
    } else {
        t[0] = t[1] = t[2] = t[3] = __float2bfloat16(0.0f);  // zero row N
    }
    *(ushort4*)(xb + i) = *(ushort4*)t;
}

// WT[k][d][c] = W[k][c][d]  (bf16; B-fragments are contiguous 16B per lane)
__global__ void cast_w_kernel(const float* __restrict__ W1, const float* __restrict__ W2,
                              __hip_bfloat16* __restrict__ W1T, __hip_bfloat16* __restrict__ W2T) {
    int idx = blockIdx.x * 256 + threadIdx.x;
    if (idx >= 27 * 4096) return;
    int k = idx >> 12, rem = idx & 4095;
    int d = rem >> 6, c = rem & 63;
    int src = k * 4096 + c * 64 + d;
    W1T[idx] = __float2bfloat16(W1[src]);
    W2T[idx] = __float2bfloat16(W2[src]);
}

// ---------------- conv kernel ----------------
// block = 4 waves; wave computes 32 rows (2 MFMA row-tiles) x 64 cols.

__global__ __launch_bounds__(256, 2) void conv_kernel(
    const __hip_bfloat16* __restrict__ xb,   // [(N+1)*64]
    const __hip_bfloat16* __restrict__ WT,   // [27*64*64]
    const int* __restrict__ nbrT,            // [27*NP]
    __hip_bfloat16* __restrict__ h,          // [N*64] bf16
    float* __restrict__ sums)                // [128]: sum[64], sumsq[64]
{
    const int tid  = threadIdx.x;
    const int lane = tid & 63;
    const int wave = tid >> 6;
    const int m    = lane & 15;
    const int quad = lane >> 4;
    const int blockbase = blockIdx.x * 128;
    const int rbase = blockbase + wave * 32;           // 32 rows per wave

    __shared__ int   sidx[27 * 128];                   // idx staging: plane x row
    __shared__ float lsum[16][64];
    __shared__ float lsq[16][64];

    // ---- stage all neighbor indices for this block's 128 rows ----
    for (int j = tid; j < 27 * 128; j += 256)
        sidx[j] = nbrT[(long)(j >> 7) * NP + blockbase + (j & 127)];
    __syncthreads();

    f32x4 acc[8];   // [tile*4 + ctile]
#pragma unroll
    for (int i = 0; i < 8; ++i) acc[i] = (f32x4){0.f, 0.f, 0.f, 0.f};

    const __hip_bfloat16* __restrict__ wfrag = WT + m * 64 + quad * 8;
    const int sbase = wave * 32 + m;                   // lane's row slot in sidx plane

    int id0[3], id1[3];        // idx ring (from LDS), depth 3
    bf16x8 A[5][2][2];         // A ring, depth 5: [stage][tile][half]
    bf16x8 B[3][8];            // B ring, depth 3: [stage][ct*2+half]

    // ---- prologue ----
    // B(0), B(1)
#pragma unroll
    for (int s = 0; s < 2; ++s) {
        const __hip_bfloat16* wk = wfrag + s * 4096;
#pragma unroll
        for (int ct = 0; ct < 4; ++ct) {
            B[s][ct * 2]     = *(const bf16x8*)(wk + ct * 1024);
            B[s][ct * 2 + 1] = *(const bf16x8*)(wk + ct * 1024 + 32);
        }
    }
    // A(0..3) (idx read directly from LDS)
#pragma unroll
    for (int s = 0; s < 4; ++s) {
        int i0 = sidx[s * 128 + sbase];
        int i1 = sidx[s * 128 + sbase + 16];
        const __hip_bfloat16* r0 = xb + (long)i0 * 64 + quad * 8;
        A[s][0][0] = *(const bf16x8*)r0;  A[s][0][1] = *(const bf16x8*)(r0 + 32);
        const __hip_bfloat16* r1 = xb + (long)i1 * 64 + quad * 8;
        A[s][1][0] = *(const bf16x8*)r1;  A[s][1][1] = *(const bf16x8*)(r1 + 32);
    }
    // idx ring: planes 4, 5
    id0[4 % 3] = sidx[4 * 128 + sbase];  id1[4 % 3] = sidx[4 * 128 + sbase + 16];
    id0[5 % 3] = sidx[5 * 128 + sbase];  id1[5 % 3] = sidx[5 * 128 + sbase + 16];
    __builtin_amdgcn_sched_barrier(0);

    // ---- pinned main loop ----
#pragma unroll
    for (int k = 0; k < 27; ++k) {
        // 1) idx (LDS -> reg), plane k+6
        if (k + 6 < 27) {
            id0[(k + 6) % 3] = sidx[(k + 6) * 128 + sbase];
            id1[(k + 6) % 3] = sidx[(k + 6) * 128 + sbase + 16];
        }
        // 2) B prefetch, plane k+2
        if (k + 2 < 27) {
            const __hip_bfloat16* wk = wfrag + (k + 2) * 4096;
#pragma unroll
            for (int ct = 0; ct < 4; ++ct) {
                B[(k + 2) % 3][ct * 2]     = *(const bf16x8*)(wk + ct * 1024);
                B[(k + 2) % 3][ct * 2 + 1] = *(const bf16x8*)(wk + ct * 1024 + 32);
            }
        }
        // 3) A prefetch, plane k+4
        if (k + 4 < 27) {
            const int s = (k + 4) % 5;
            const __hip_bfloat16* r0 = xb + (long)id0[(k + 4) % 3] * 64 + quad * 8;
            A[s][0][0] = *(const bf16x8*)r0;  A[s][0][1] = *(const bf16x8*)(r0 + 32);
            const __hip_bfloat16* r1 = xb + (long)id1[(k + 4) % 3] * 64 + quad * 8;
            A[s][1][0] = *(const bf16x8*)r1;  A[s][1][1] = *(const bf16x8*)(r1 + 32);
        }
        __builtin_amdgcn_sched_barrier(0);
        // 4) MFMA for plane k
        const int cs = k % 5, bs = k % 3;
#pragma unroll
        for (int ct = 0; ct < 4; ++ct) {
            acc[ct]     = __builtin_amdgcn_mfma_f32_16x16x32_bf16(A[cs][0][0], B[bs][ct * 2],     acc[ct],     0, 0, 0);
            acc[ct]     = __builtin_amdgcn_mfma_f32_16x16x32_bf16(A[cs][0][1], B[bs][ct * 2 + 1], acc[ct],     0, 0, 0);
            acc[4 + ct] = __builtin_amdgcn_mfma_f32_16x16x32_bf16(A[cs][1][0], B[bs][ct * 2],     acc[4 + ct], 0, 0, 0);
            acc[4 + ct] = __builtin_amdgcn_mfma_f32_16x16x32_bf16(A[cs][1][1], B[bs][ct * 2 + 1], acc[4 + ct], 0, 0, 0);
        }
        __builtin_amdgcn_sched_barrier(0);
    }

    const bool valid = rbase < N_VOX;   // whole wave-tile valid or not

    // store h (bf16; BN stats below use the fp32 registers)
    if (valid) {
#pragma unroll
        for (int t = 0; t < 2; ++t) {
            __hip_bfloat16* hp = h + (long)(rbase + t * 16 + quad * 4) * 64 + m;
#pragma unroll
            for (int r = 0; r < 4; ++r) {
#pragma unroll
                for (int ct = 0; ct < 4; ++ct)
                    hp[r * 64 + ct * 16] = __float2bfloat16(acc[t * 4 + ct][r]);
            }
        }
    }

    // fused BN stats: per-channel sum / sumsq over this wave's 32 rows
#pragma unroll
    for (int ct = 0; ct < 4; ++ct) {
        float s = 0.f, q = 0.f;
        if (valid) {
#pragma unroll
            for (int t = 0; t < 2; ++t)
#pragma unroll
                for (int r = 0; r < 4; ++r) {
                    float v = acc[t * 4 + ct][r];
                    s += v; q += v * v;
                }
        }
        lsum[wave * 4 + quad][ct * 16 + m] = s;
        lsq [wave * 4 + quad][ct * 16 + m] = q;
    }
    __syncthreads();
    if (tid < 64) {
        float S = 0.f, Q = 0.f;
#pragma unroll
        for (int j = 0; j < 16; ++j) { S += lsum[j][tid]; Q += lsq[j][tid]; }
        atomicAdd(&sums[tid], S);
        atomicAdd(&sums[64 + tid], Q);
    }
}

// ---------------- BN1 + relu + cast to bf16 (conv2 input) ----------------

__global__ void bnrelu_kernel(const __hip_bfloat16* __restrict__ h, const float* __restrict__ sums,
                              const float* __restrict__ gamma, const float* __restrict__ beta,
                              __hip_bfloat16* __restrict__ hb) {
    long i = ((long)blockIdx.x * 256 + threadIdx.x) * 4;
    if (i >= (long)(N_VOX + 1) * 64) return;
    __hip_bfloat16 t[4];
    if (i < (long)N_VOX * 64) {
        int c0 = (int)(i & 63);
        ushort4 raw = *(const ushort4*)(h + i);
        __hip_bfloat16 hv[4];
        *(ushort4*)hv = raw;
#pragma unroll
        for (int j = 0; j < 4; ++j) {
            int c = c0 + j;
            float mu  = sums[c] * (1.0f / N_VOX);
            float var = sums[64 + c] * (1.0f / N_VOX) - mu * mu;
            float rs  = rsqrtf(var + EPS_BN);
            float val = gamma[c] * (__bfloat162float(hv[j]) - mu) * rs + beta[c];
            t[j] = __float2bfloat16(fmaxf(val, 0.0f));
        }
    } else {
        t[0] = t[1] = t[2] = t[3] = __float2bfloat16(0.0f);   // zero row N
    }
    *(ushort4*)(hb + i) = *(ushort4*)t;
}

// ---------------- BN2 + residual + relu -> d_out ----------------

__global__ void final_kernel(const __hip_bfloat16* __restrict__ h, const float* __restrict__ x,
                             const float* __restrict__ sums, const float* __restrict__ gamma,
                             const float* __restrict__ beta, float* __restrict__ out) {
    long i = ((long)blockIdx.x * 256 + threadIdx.x) * 4;
    if (i >= (long)N_VOX * 64) return;
    int c0 = (int)(i & 63);
    ushort4 raw = *(const ushort4*)(h + i);
    __hip_bfloat16 hv[4];
    *(ushort4*)hv = raw;
    float4 xr = *(const float4*)(x + i);
    float xx[4] = {xr.x, xr.y, xr.z, xr.w};
    float oo[4];
#pragma unroll
    for (int j = 0; j < 4; ++j) {
        int c = c0 + j;
        float mu  = sums[c] * (1.0f / N_VOX);
        float var = sums[64 + c] * (1.0f / N_VOX) - mu * mu;
        float rs  = rsqrtf(var + EPS_BN);
        float val = gamma[c] * (__bfloat162float(hv[j]) - mu) * rs + beta[c] + xx[j];
        oo[j] = fmaxf(val, 0.0f);
    }
    float4 ov = {oo[0], oo[1], oo[2], oo[3]};
    *(float4*)(out + i) = ov;
}

// ---------------- launcher ----------------

extern "C" void kernel_launch(void* const* d_in, const int* in_sizes, int n_in,
                              void* d_out, int out_size, void* d_ws, size_t ws_size,
                              hipStream_t stream) {
    const float* x      = (const float*)d_in[0];
    const float* W1     = (const float*)d_in[1];
    const float* gamma1 = (const float*)d_in[2];
    const float* beta1  = (const float*)d_in[3];
    const float* W2     = (const float*)d_in[4];
    const float* gamma2 = (const float*)d_in[5];
    const float* beta2  = (const float*)d_in[6];
    const int* in_maps  = (const int*)d_in[7];
    const int* out_maps = (const int*)d_in[8];
    float* out = (float*)d_out;

    char* ws = (char*)d_ws;
    size_t off = 0;
    auto alloc = [&](size_t bytes) -> void* {
        void* p = ws + off;
        off = (off + bytes + 255) & ~(size_t)255;
        return p;
    };
    int* nbrT           = (int*)alloc((size_t)27 * NP * 4);                    // 21.6 MB
    __hip_bfloat16* xb  = (__hip_bfloat16*)alloc((size_t)(N_VOX + 1) * 64 * 2); // 25.6 MB (reused as h1b)
    __hip_bfloat16* W1T = (__hip_bfloat16*)alloc((size_t)27 * 4096 * 2);
    __hip_bfloat16* W2T = (__hip_bfloat16*)alloc((size_t)27 * 4096 * 2);
    __hip_bfloat16* h   = (__hip_bfloat16*)alloc((size_t)N_VOX * 64 * 2);      // 25.6 MB
    float* sums         = (float*)alloc(256 * 4);
    __hip_bfloat16* h1b = xb;   // xb dead after conv1; reuse for BN1(relu) output

    const long elem_x = (long)(N_VOX + 1) * 64;

    fill_kernel   <<<dim3((NP / 4 + 255) / 256, 27), 256, 0, stream>>>(nbrT, sums);
    scatter_kernel<<<26 * P_PAIR / 256, 256, 0, stream>>>(out_maps, in_maps, nbrT);
    cast_x_kernel <<<(int)((elem_x / 4 + 255) / 256), 256, 0, stream>>>(x, xb);
    cast_w_kernel <<<(27 * 4096 + 255) / 256, 256, 0, stream>>>(W1, W2, W1T, W2T);

    conv_kernel   <<<NP / 128, 256, 0, stream>>>(xb, W1T, nbrT, h, sums);
    bnrelu_kernel <<<(int)((elem_x / 4 + 255) / 256), 256, 0, stream>>>(h, sums, gamma1, beta1, h1b);

    conv_kernel   <<<NP / 128, 256, 0, stream>>>(h1b, W2T, nbrT, h, sums + 128);
    final_kernel  <<<(int)(((long)N_VOX * 64 / 4 + 255) / 256), 256, 0, stream>>>(h, x, sums + 128, gamma2, beta2, out);
}

// Round 6
// 376.914 us; speedup vs baseline: 1.6235x; 1.6235x over previous
//
#include <hip/hip_runtime.h>
#include <hip/hip_bf16.h>

// BasicBlock sparse conv v6: output-centric gather conv, bf16 MFMA.
// v3-v5 post-mortem: conv time fits ~1 vmem lane-address/cyc/CU (TA-bound),
// serialized across waves -> pipeline depth irrelevant. v6 cuts addresses:
//  (1) weights pre-swizzled to MFMA lane order -> B loads fully coalesced
//      (64 lanes x 16B contiguous, TA fast path)
//  (2) A gathers exec-masked on idx<N (~70% lanes are sentinel -> no address
//      generated for inactive lanes), zero-fill fragment otherwise.

#define N_VOX 200000
#define NP 200064            // padded rows: 1563 blocks * 128 rows
#define P_PAIR 65536
#define EPS_BN 1e-5f

typedef __attribute__((ext_vector_type(8))) short bf16x8;   // 8 bf16 = 4 VGPRs
typedef __attribute__((ext_vector_type(4))) float f32x4;

// ---------------- prep kernels ----------------

__global__ void fill_kernel(int* __restrict__ nbrT, float* __restrict__ sums) {
    int p = blockIdx.y;                                   // plane 0..26
    long i = ((long)blockIdx.x * 256 + threadIdx.x) * 4;  // element in plane
    if (i < NP) {
        int4 v;
        if (p == 13) {   // identity plane (center tap); pad rows -> zero row
            v.x = (i + 0 < N_VOX) ? (int)i + 0 : N_VOX;
            v.y = (i + 1 < N_VOX) ? (int)i + 1 : N_VOX;
            v.z = (i + 2 < N_VOX) ? (int)i + 2 : N_VOX;
            v.w = (i + 3 < N_VOX) ? (int)i + 3 : N_VOX;
        } else {
            v.x = v.y = v.z = v.w = N_VOX;                // sentinel
        }
        *(int4*)(nbrT + (long)p * NP + i) = v;
    }
    if (p == 0 && blockIdx.x == 0 && threadIdx.x < 64) {  // zero sums[256]
        float4 z = {0.f, 0.f, 0.f, 0.f};
        ((float4*)sums)[threadIdx.x] = z;
    }
}

__global__ void scatter_kernel(const int* __restrict__ out_maps,
                               const int* __restrict__ in_maps,
                               int* __restrict__ nbrT) {
    int idx = blockIdx.x * 256 + threadIdx.x;       // < 26*65536
    int o = out_maps[idx];
    if (o < N_VOX) {
        int k = idx >> 16;                          // offset index 0..25
        int p = k + (k >= 13);                      // weight plane (skip center)
        nbrT[(long)p * NP + o] = in_maps[idx];
    }
}

__global__ void cast_x_kernel(const float* __restrict__ x,
                              __hip_bfloat16* __restrict__ xb) {
    long i = ((long)blockIdx.x * 256 + threadIdx.x) * 4;
    if (i >= (long)(N_VOX + 1) * 64) return;
    __hip_bfloat16 t[4];
    if (i < (long)N_VOX * 64) {
        float4 v = *(const float4*)(x + i);
        t[0] = __float2bfloat16(v.x); t[1] = __float2bfloat16(v.y);
        t[2] = __float2bfloat16(v.z); t[3] = __float2bfloat16(v.w);
    } else {
        t[0] = t[1] = t[2] = t[3] = __float2bfloat16(0.0f);  // zero row N
    }
    *(ushort4*)(xb + i) = *(ushort4*)t;
}

// W4: weights swizzled to MFMA B-fragment lane order.
// W4[((k*8 + ct*2 + half)*64 + lane)*8 + j] = W[k][c][d],
//   lane = quad*16 + m, c = half*32 + quad*8 + j, d = ct*16 + m.
// -> in-kernel B load for (k,ct,half) is lane-contiguous 16B (1KB/instr).
__global__ void cast_w_kernel(const float* __restrict__ W1, const float* __restrict__ W2,
                              __hip_bfloat16* __restrict__ W1S, __hip_bfloat16* __restrict__ W2S) {
    int idx = blockIdx.x * 256 + threadIdx.x;
    if (idx >= 27 * 4096) return;
    int j    = idx & 7;
    int lane = (idx >> 3) & 63;
    int g    = idx >> 9;           // k*8 + ct*2 + half
    int half = g & 1, ct = (g >> 1) & 3, k = g >> 3;
    int m = lane & 15, quad = lane >> 4;
    int c = half * 32 + quad * 8 + j;
    int d = ct * 16 + m;
    int src = k * 4096 + c * 64 + d;
    W1S[idx] = __float2bfloat16(W1[src]);
    W2S[idx] = __float2bfloat16(W2[src]);
}

// ---------------- conv kernel ----------------
// block = 4 waves; wave computes 32 rows (2 MFMA row-tiles) x 64 cols.
// Per iter k: A(k+2) masked-gather | B(k+1) coalesced | fence | MFMA(k) | fence.

__global__ __launch_bounds__(256, 2) void conv_kernel(
    const __hip_bfloat16* __restrict__ xb,   // [(N+1)*64]
    const __hip_bfloat16* __restrict__ W4,   // [27*4096] swizzled
    const int* __restrict__ nbrT,            // [27*NP]
    __hip_bfloat16* __restrict__ h,          // [N*64] bf16
    float* __restrict__ sums)                // [128]: sum[64], sumsq[64]
{
    const int tid  = threadIdx.x;
    const int lane = tid & 63;
    const int wave = tid >> 6;
    const int m    = lane & 15;
    const int quad = lane >> 4;
    const int blockbase = blockIdx.x * 128;
    const int rbase = blockbase + wave * 32;           // 32 rows per wave

    __shared__ int   sidx[27 * 128];                   // idx staging: plane x row
    __shared__ float lsum[16][64];
    __shared__ float lsq[16][64];

    // ---- stage all neighbor indices for this block's 128 rows ----
    for (int j = tid; j < 27 * 128; j += 256)
        sidx[j] = nbrT[(long)(j >> 7) * NP + blockbase + (j & 127)];
    __syncthreads();

    f32x4 acc[8];   // [tile*4 + ctile]
#pragma unroll
    for (int i = 0; i < 8; ++i) acc[i] = (f32x4){0.f, 0.f, 0.f, 0.f};

    const __hip_bfloat16* __restrict__ wl = W4 + lane * 8;   // coalesced B base
    const int sbase = wave * 32 + m;                   // lane's row slot in sidx plane
    const bf16x8 z8 = {0, 0, 0, 0, 0, 0, 0, 0};

    bf16x8 A[3][2][2];         // A ring, depth 3: [stage][tile][half]
    bf16x8 B[2][8];            // B ring, depth 2: [stage][ct*2+half]

    // masked A gather for plane p into stage s
#define LOAD_A(s, p)                                                          \
    {                                                                         \
        int i0 = sidx[(p) * 128 + sbase];                                     \
        int i1 = sidx[(p) * 128 + sbase + 16];                                \
        if (i0 < N_VOX) {                                                     \
            const __hip_bfloat16* r0 = xb + (long)i0 * 64 + quad * 8;         \
            A[s][0][0] = *(const bf16x8*)r0;                                  \
            A[s][0][1] = *(const bf16x8*)(r0 + 32);                           \
        } else { A[s][0][0] = z8; A[s][0][1] = z8; }                          \
        if (i1 < N_VOX) {                                                     \
            const __hip_bfloat16* r1 = xb + (long)i1 * 64 + quad * 8;         \
            A[s][1][0] = *(const bf16x8*)r1;                                  \
            A[s][1][1] = *(const bf16x8*)(r1 + 32);                           \
        } else { A[s][1][0] = z8; A[s][1][1] = z8; }                          \
    }

#define LOAD_B(bs, p)                                                         \
    {                                                                         \
        const __hip_bfloat16* wk = wl + (p) * 4096;                           \
        _Pragma("unroll")                                                     \
        for (int q = 0; q < 8; ++q)                                           \
            B[bs][q] = *(const bf16x8*)(wk + q * 512);                        \
    }

    // ---- prologue: A(0), A(1), B(0) ----
    LOAD_A(0, 0)
    LOAD_A(1, 1)
    LOAD_B(0, 0)
    __builtin_amdgcn_sched_barrier(0);

    // ---- main loop ----
#pragma unroll
    for (int k = 0; k < 27; ++k) {
        // A prefetch, plane k+2 (masked gather; idx straight from LDS)
        if (k + 2 < 27) LOAD_A((k + 2) % 3, k + 2)
        // B prefetch, plane k+1 (coalesced)
        if (k + 1 < 27) LOAD_B((k + 1) & 1, k + 1)
        __builtin_amdgcn_sched_barrier(0);
        // MFMA for plane k
        const int cs = k % 3, bs = k & 1;
#pragma unroll
        for (int ct = 0; ct < 4; ++ct) {
            acc[ct]     = __builtin_amdgcn_mfma_f32_16x16x32_bf16(A[cs][0][0], B[bs][ct * 2],     acc[ct],     0, 0, 0);
            acc[ct]     = __builtin_amdgcn_mfma_f32_16x16x32_bf16(A[cs][0][1], B[bs][ct * 2 + 1], acc[ct],     0, 0, 0);
            acc[4 + ct] = __builtin_amdgcn_mfma_f32_16x16x32_bf16(A[cs][1][0], B[bs][ct * 2],     acc[4 + ct], 0, 0, 0);
            acc[4 + ct] = __builtin_amdgcn_mfma_f32_16x16x32_bf16(A[cs][1][1], B[bs][ct * 2 + 1], acc[4 + ct], 0, 0, 0);
        }
        __builtin_amdgcn_sched_barrier(0);
    }
#undef LOAD_A
#undef LOAD_B

    const bool valid = rbase < N_VOX;   // whole wave-tile valid or not

    // store h (bf16; BN stats below use the fp32 registers)
    if (valid) {
#pragma unroll
        for (int t = 0; t < 2; ++t) {
            __hip_bfloat16* hp = h + (long)(rbase + t * 16 + quad * 4) * 64 + m;
#pragma unroll
            for (int r = 0; r < 4; ++r) {
#pragma unroll
                for (int ct = 0; ct < 4; ++ct)
                    hp[r * 64 + ct * 16] = __float2bfloat16(acc[t * 4 + ct][r]);
            }
        }
    }

    // fused BN stats: per-channel sum / sumsq over this wave's 32 rows
#pragma unroll
    for (int ct = 0; ct < 4; ++ct) {
        float s = 0.f, q = 0.f;
        if (valid) {
#pragma unroll
            for (int t = 0; t < 2; ++t)
#pragma unroll
                for (int r = 0; r < 4; ++r) {
                    float v = acc[t * 4 + ct][r];
                    s += v; q += v * v;
                }
        }
        lsum[wave * 4 + quad][ct * 16 + m] = s;
        lsq [wave * 4 + quad][ct * 16 + m] = q;
    }
    __syncthreads();
    if (tid < 64) {
        float S = 0.f, Q = 0.f;
#pragma unroll
        for (int j = 0; j < 16; ++j) { S += lsum[j][tid]; Q += lsq[j][tid]; }
        atomicAdd(&sums[tid], S);
        atomicAdd(&sums[64 + tid], Q);
    }
}

// ---------------- BN1 + relu + cast to bf16 (conv2 input) ----------------

__global__ void bnrelu_kernel(const __hip_bfloat16* __restrict__ h, const float* __restrict__ sums,
                              const float* __restrict__ gamma, const float* __restrict__ beta,
                              __hip_bfloat16* __restrict__ hb) {
    long i = ((long)blockIdx.x * 256 + threadIdx.x) * 4;
    if (i >= (long)(N_VOX + 1) * 64) return;
    __hip_bfloat16 t[4];
    if (i < (long)N_VOX * 64) {
        int c0 = (int)(i & 63);
        ushort4 raw = *(const ushort4*)(h + i);
        __hip_bfloat16 hv[4];
        *(ushort4*)hv = raw;
#pragma unroll
        for (int j = 0; j < 4; ++j) {
            int c = c0 + j;
            float mu  = sums[c] * (1.0f / N_VOX);
            float var = sums[64 + c] * (1.0f / N_VOX) - mu * mu;
            float rs  = rsqrtf(var + EPS_BN);
            float val = gamma[c] * (__bfloat162float(hv[j]) - mu) * rs + beta[c];
            t[j] = __float2bfloat16(fmaxf(val, 0.0f));
        }
    } else {
        t[0] = t[1] = t[2] = t[3] = __float2bfloat16(0.0f);   // zero row N
    }
    *(ushort4*)(hb + i) = *(ushort4*)t;
}

// ---------------- BN2 + residual + relu -> d_out ----------------

__global__ void final_kernel(const __hip_bfloat16* __restrict__ h, const float* __restrict__ x,
                             const float* __restrict__ sums, const float* __restrict__ gamma,
                             const float* __restrict__ beta, float* __restrict__ out) {
    long i = ((long)blockIdx.x * 256 + threadIdx.x) * 4;
    if (i >= (long)N_VOX * 64) return;
    int c0 = (int)(i & 63);
    ushort4 raw = *(const ushort4*)(h + i);
    __hip_bfloat16 hv[4];
    *(ushort4*)hv = raw;
    float4 xr = *(const float4*)(x + i);
    float xx[4] = {xr.x, xr.y, xr.z, xr.w};
    float oo[4];
#pragma unroll
    for (int j = 0; j < 4; ++j) {
        int c = c0 + j;
        float mu  = sums[c] * (1.0f / N_VOX);
        float var = sums[64 + c] * (1.0f / N_VOX) - mu * mu;
        float rs  = rsqrtf(var + EPS_BN);
        float val = gamma[c] * (__bfloat162float(hv[j]) - mu) * rs + beta[c] + xx[j];
        oo[j] = fmaxf(val, 0.0f);
    }
    float4 ov = {oo[0], oo[1], oo[2], oo[3]};
    *(float4*)(out + i) = ov;
}

// ---------------- launcher ----------------

extern "C" void kernel_launch(void* const* d_in, const int* in_sizes, int n_in,
                              void* d_out, int out_size, void* d_ws, size_t ws_size,
                              hipStream_t stream) {
    const float* x      = (const float*)d_in[0];
    const float* W1     = (const float*)d_in[1];
    const float* gamma1 = (const float*)d_in[2];
    const float* beta1  = (const float*)d_in[3];
    const float* W2     = (const float*)d_in[4];
    const float* gamma2 = (const float*)d_in[5];
    const float* beta2  = (const float*)d_in[6];
    const int* in_maps  = (const int*)d_in[7];
    const int* out_maps = (const int*)d_in[8];
    float* out = (float*)d_out;

    char* ws = (char*)d_ws;
    size_t off = 0;
    auto alloc = [&](size_t bytes) -> void* {
        void* p = ws + off;
        off = (off + bytes + 255) & ~(size_t)255;
        return p;
    };
    int* nbrT           = (int*)alloc((size_t)27 * NP * 4);                    // 21.6 MB
    __hip_bfloat16* xb  = (__hip_bfloat16*)alloc((size_t)(N_VOX + 1) * 64 * 2); // 25.6 MB (reused as h1b)
    __hip_bfloat16* W1S = (__hip_bfloat16*)alloc((size_t)27 * 4096 * 2);
    __hip_bfloat16* W2S = (__hip_bfloat16*)alloc((size_t)27 * 4096 * 2);
    __hip_bfloat16* h   = (__hip_bfloat16*)alloc((size_t)N_VOX * 64 * 2);      // 25.6 MB
    float* sums         = (float*)alloc(256 * 4);
    __hip_bfloat16* h1b = xb;   // xb dead after conv1; reuse for BN1(relu) output

    const long elem_x = (long)(N_VOX + 1) * 64;

    fill_kernel   <<<dim3((NP / 4 + 255) / 256, 27), 256, 0, stream>>>(nbrT, sums);
    scatter_kernel<<<26 * P_PAIR / 256, 256, 0, stream>>>(out_maps, in_maps, nbrT);
    cast_x_kernel <<<(int)((elem_x / 4 + 255) / 256), 256, 0, stream>>>(x, xb);
    cast_w_kernel <<<(27 * 4096 + 255) / 256, 256, 0, stream>>>(W1, W2, W1S, W2S);

    conv_kernel   <<<NP / 128, 256, 0, stream>>>(xb, W1S, nbrT, h, sums);
    bnrelu_kernel <<<(int)((elem_x / 4 + 255) / 256), 256, 0, stream>>>(h, sums, gamma1, beta1, h1b);

    conv_kernel   <<<NP / 128, 256, 0, stream>>>(h1b, W2S, nbrT, h, sums + 128);
    final_kernel  <<<(int)(((long)N_VOX * 64 / 4 + 255) / 256), 256, 0, stream>>>(h, x, sums + 128, gamma2, beta2, out);
}

// Round 7
// 295.037 us; speedup vs baseline: 2.0741x; 1.2775x over previous
//
#include <hip/hip_runtime.h>
#include <hip/hip_bf16.h>

// BasicBlock sparse conv v7: output-centric gather conv, bf16 MFMA.
// TA-address model (v6-confirmed): time ~ vmem lane-addresses/CU.
// v7 cuts the two dominant address streams:
//  - B weights: LDS double-buffer shared by 4 waves (each wave stages 2KB/plane,
//    ds_read_b128 for fragments) -> 8x fewer B vmem addresses per row.
//  - h stores: wave-private LDS transpose -> 8 dwordx4 stores/wave vs 64 scalar.
// 64 rows/wave (4 row-tiles), one __syncthreads per plane (dbuf swap).

#define N_VOX 200000
#define NP 200192            // padded rows: 782 blocks * 256 rows
#define EPS_BN 1e-5f

typedef __attribute__((ext_vector_type(8))) short bf16x8;   // 8 bf16 = 4 VGPRs
typedef __attribute__((ext_vector_type(4))) float f32x4;

// ---------------- prep kernels ----------------

__global__ void fill_kernel(int* __restrict__ nbrT, float* __restrict__ sums) {
    int p = blockIdx.y;                                   // plane 0..26
    long i = ((long)blockIdx.x * 256 + threadIdx.x) * 4;  // element in plane
    if (i < NP) {
        int4 v;
        if (p == 13) {   // identity plane (center tap); pad rows -> zero row
            v.x = (i + 0 < N_VOX) ? (int)i + 0 : N_VOX;
            v.y = (i + 1 < N_VOX) ? (int)i + 1 : N_VOX;
            v.z = (i + 2 < N_VOX) ? (int)i + 2 : N_VOX;
            v.w = (i + 3 < N_VOX) ? (int)i + 3 : N_VOX;
        } else {
            v.x = v.y = v.z = v.w = N_VOX;                // sentinel
        }
        *(int4*)(nbrT + (long)p * NP + i) = v;
    }
    if (p == 0 && blockIdx.x == 0 && threadIdx.x < 64) {  // zero sums[256]
        float4 z = {0.f, 0.f, 0.f, 0.f};
        ((float4*)sums)[threadIdx.x] = z;
    }
}

__global__ void scatter_kernel(const int* __restrict__ out_maps,
                               const int* __restrict__ in_maps,
                               int* __restrict__ nbrT) {
    int idx = blockIdx.x * 256 + threadIdx.x;       // < 26*65536
    int o = out_maps[idx];
    if (o < N_VOX) {
        int k = idx >> 16;                          // offset index 0..25
        int p = k + (k >= 13);                      // weight plane (skip center)
        nbrT[(long)p * NP + o] = in_maps[idx];
    }
}

__global__ void cast_x_kernel(const float* __restrict__ x,
                              __hip_bfloat16* __restrict__ xb) {
    long i = ((long)blockIdx.x * 256 + threadIdx.x) * 4;
    if (i >= (long)(N_VOX + 1) * 64) return;
    __hip_bfloat16 t[4];
    if (i < (long)N_VOX * 64) {
        float4 v = *(const float4*)(x + i);
        t[0] = __float2bfloat16(v.x); t[1] = __float2bfloat16(v.y);
        t[2] = __float2bfloat16(v.z); t[3] = __float2bfloat16(v.w);
    } else {
        t[0] = t[1] = t[2] = t[3] = __float2bfloat16(0.0f);  // zero row N
    }
    *(ushort4*)(xb + i) = *(ushort4*)t;
}

// W4: weights swizzled to MFMA B-fragment lane order.
// W4[((k*8 + g)*64 + lane)*8 + j],  g = ct*2+half, c = half*32+quad*8+j, d = ct*16+m.
__global__ void cast_w_kernel(const float* __restrict__ W1, const float* __restrict__ W2,
                              __hip_bfloat16* __restrict__ W1S, __hip_bfloat16* __restrict__ W2S) {
    int idx = blockIdx.x * 256 + threadIdx.x;
    if (idx >= 27 * 4096) return;
    int j    = idx & 7;
    int lane = (idx >> 3) & 63;
    int g    = idx >> 9;           // k*8 + ct*2 + half
    int half = g & 1, ct = (g >> 1) & 3, k = g >> 3;
    int m = lane & 15, quad = lane >> 4;
    int c = half * 32 + quad * 8 + j;
    int d = ct * 16 + m;
    int src = k * 4096 + c * 64 + d;
    W1S[idx] = __float2bfloat16(W1[src]);
    W2S[idx] = __float2bfloat16(W2[src]);
}

// ---------------- conv kernel ----------------
// block = 4 waves x 64 rows = 256 rows, cout 64.
// Iter k: barrier | ds_write B(k+1) | vload B(k+2) | A-gather(k+2) | MFMA(k).

__global__ __launch_bounds__(256, 2) void conv_kernel(
    const __hip_bfloat16* __restrict__ xb,   // [(N+1)*64]
    const __hip_bfloat16* __restrict__ W4,   // [27*4096] swizzled
    const int* __restrict__ nbrT,            // [27*NP]
    __hip_bfloat16* __restrict__ h,          // [N*64] bf16
    float* __restrict__ sums)                // [128]: sum[64], sumsq[64]
{
    const int tid  = threadIdx.x;
    const int lane = tid & 63;
    const int wave = tid >> 6;
    const int m    = lane & 15;
    const int quad = lane >> 4;
    const int blockbase = blockIdx.x * 256;
    const int rbase = blockbase + wave * 64;           // 64 rows per wave

    __shared__ __align__(16) char smem[52224];
    int*            sidx = (int*)smem;                           // [27*256], 27648B
    __hip_bfloat16* bbuf = (__hip_bfloat16*)(smem + 27648);      // [2][4096],16384B
    float*          lsum = (float*)(smem + 44032);               // [16][64], 4096B
    float*          lsq  = (float*)(smem + 48128);               // [16][64], 4096B
    __hip_bfloat16* trans = (__hip_bfloat16*)(smem + wave * 9216); // [64][72] post-loop (overlaps sidx/bbuf)

    // ---- stage neighbor indices (27 planes x 256 rows) ----
    for (int j = tid; j < 27 * 256; j += 256)
        sidx[j] = nbrT[(long)(j >> 8) * NP + blockbase + (j & 255)];

    // ---- stage B(0) into bbuf[0]: each wave 2 chunks of 1KB ----
    {
        const __hip_bfloat16* ws = W4 + wave * 1024 + lane * 8;
        bf16x8 b0 = *(const bf16x8*)(ws);
        bf16x8 b1 = *(const bf16x8*)(ws + 512);
        __hip_bfloat16* bd = bbuf + wave * 1024 + lane * 8;
        *(bf16x8*)bd = b0;
        *(bf16x8*)(bd + 512) = b1;
    }
    __syncthreads();

    f32x4 acc[16];   // [tile*4 + ctile], 4 tiles x 4 ctiles
#pragma unroll
    for (int i = 0; i < 16; ++i) acc[i] = (f32x4){0.f, 0.f, 0.f, 0.f};

    const bf16x8 z8 = {0, 0, 0, 0, 0, 0, 0, 0};
    bf16x8 A[3][4][2];     // A ring depth 3: [stage][tile][half]
    bf16x8 btr0, btr1;     // B transit regs (next plane to ds_write)

#define LOAD_A(s, p)                                                        \
    {                                                                       \
        _Pragma("unroll")                                                   \
        for (int t = 0; t < 4; ++t) {                                       \
            int ii = sidx[(p) * 256 + wave * 64 + t * 16 + m];              \
            if (ii < N_VOX) {                                               \
                const __hip_bfloat16* rr = xb + (long)ii * 64 + quad * 8;   \
                A[s][t][0] = *(const bf16x8*)rr;                            \
                A[s][t][1] = *(const bf16x8*)(rr + 32);                     \
            } else { A[s][t][0] = z8; A[s][t][1] = z8; }                    \
        }                                                                   \
    }

#define LOAD_BT(p)                                                          \
    {                                                                       \
        const __hip_bfloat16* ws = W4 + (p) * 4096 + wave * 1024 + lane * 8;\
        btr0 = *(const bf16x8*)(ws);                                        \
        btr1 = *(const bf16x8*)(ws + 512);                                  \
    }

    // prologue: B(1) transit, A(0), A(1)
    LOAD_BT(1)
    LOAD_A(0, 0)
    LOAD_A(1, 1)

#pragma unroll
    for (int k = 0; k < 27; ++k) {
        __syncthreads();   // bbuf[k&1] writes visible; prior reads of bbuf[(k+1)&1] done
        if (k + 1 < 27) {  // ds_write B(k+1) -> bbuf[(k+1)&1]
            __hip_bfloat16* bd = bbuf + ((k + 1) & 1) * 4096 + wave * 1024 + lane * 8;
            *(bf16x8*)bd = btr0;
            *(bf16x8*)(bd + 512) = btr1;
        }
        if (k + 2 < 27) {
            LOAD_BT(k + 2)
            LOAD_A((k + 2) % 3, k + 2)
        }
        __builtin_amdgcn_sched_barrier(0);
        // MFMA(k): B frags from bbuf[k&1] via ds_read_b128
        const __hip_bfloat16* bb = bbuf + (k & 1) * 4096;
        const int cs = k % 3;
#pragma unroll
        for (int ct = 0; ct < 4; ++ct) {
#pragma unroll
            for (int hf = 0; hf < 2; ++hf) {
                bf16x8 b = *(const bf16x8*)(bb + (ct * 2 + hf) * 512 + lane * 8);
#pragma unroll
                for (int t = 0; t < 4; ++t)
                    acc[t * 4 + ct] = __builtin_amdgcn_mfma_f32_16x16x32_bf16(A[cs][t][hf], b, acc[t * 4 + ct], 0, 0, 0);
            }
        }
        __builtin_amdgcn_sched_barrier(0);
    }
#undef LOAD_A
#undef LOAD_BT

    __syncthreads();   // all waves done with sidx/bbuf -> trans region reusable

    const bool valid = rbase < N_VOX;   // N_VOX % 64 == 0: per-wave granularity

    // ---- fused BN stats ----
#pragma unroll
    for (int ct = 0; ct < 4; ++ct) {
        float s = 0.f, q = 0.f;
        if (valid) {
#pragma unroll
            for (int t = 0; t < 4; ++t)
#pragma unroll
                for (int r = 0; r < 4; ++r) {
                    float v = acc[t * 4 + ct][r];
                    s += v; q += v * v;
                }
        }
        lsum[(wave * 4 + quad) * 64 + ct * 16 + m] = s;
        lsq [(wave * 4 + quad) * 64 + ct * 16 + m] = q;
    }
    __syncthreads();
    if (tid < 64) {
        float S = 0.f, Q = 0.f;
#pragma unroll
        for (int j = 0; j < 16; ++j) { S += lsum[j * 64 + tid]; Q += lsq[j * 64 + tid]; }
        atomicAdd(&sums[tid], S);
        atomicAdd(&sums[64 + tid], Q);
    }

    // ---- h store via wave-private LDS transpose (bf16, coalesced dwordx4) ----
    if (valid) {
#pragma unroll
        for (int t = 0; t < 4; ++t)
#pragma unroll
            for (int r = 0; r < 4; ++r)
#pragma unroll
                for (int ct = 0; ct < 4; ++ct)
                    trans[(t * 16 + quad * 4 + r) * 72 + ct * 16 + m] =
                        __float2bfloat16(acc[t * 4 + ct][r]);
#pragma unroll
        for (int i = 0; i < 8; ++i) {
            int row = i * 8 + (lane >> 3);
            bf16x8 v = *(const bf16x8*)(trans + row * 72 + (lane & 7) * 8);
            *(bf16x8*)(h + (long)(rbase + row) * 64 + (lane & 7) * 8) = v;
        }
    }
}

// ---------------- BN1 + relu + cast to bf16 (conv2 input) ----------------

__global__ void bnrelu_kernel(const __hip_bfloat16* __restrict__ h, const float* __restrict__ sums,
                              const float* __restrict__ gamma, const float* __restrict__ beta,
                              __hip_bfloat16* __restrict__ hb) {
    long i = ((long)blockIdx.x * 256 + threadIdx.x) * 4;
    if (i >= (long)(N_VOX + 1) * 64) return;
    __hip_bfloat16 t[4];
    if (i < (long)N_VOX * 64) {
        int c0 = (int)(i & 63);
        ushort4 raw = *(const ushort4*)(h + i);
        __hip_bfloat16 hv[4];
        *(ushort4*)hv = raw;
#pragma unroll
        for (int j = 0; j < 4; ++j) {
            int c = c0 + j;
            float mu  = sums[c] * (1.0f / N_VOX);
            float var = sums[64 + c] * (1.0f / N_VOX) - mu * mu;
            float rs  = rsqrtf(var + EPS_BN);
            float val = gamma[c] * (__bfloat162float(hv[j]) - mu) * rs + beta[c];
            t[j] = __float2bfloat16(fmaxf(val, 0.0f));
        }
    } else {
        t[0] = t[1] = t[2] = t[3] = __float2bfloat16(0.0f);   // zero row N
    }
    *(ushort4*)(hb + i) = *(ushort4*)t;
}

// ---------------- BN2 + residual + relu -> d_out ----------------

__global__ void final_kernel(const __hip_bfloat16* __restrict__ h, const float* __restrict__ x,
                             const float* __restrict__ sums, const float* __restrict__ gamma,
                             const float* __restrict__ beta, float* __restrict__ out) {
    long i = ((long)blockIdx.x * 256 + threadIdx.x) * 4;
    if (i >= (long)N_VOX * 64) return;
    int c0 = (int)(i & 63);
    ushort4 raw = *(const ushort4*)(h + i);
    __hip_bfloat16 hv[4];
    *(ushort4*)hv = raw;
    float4 xr = *(const float4*)(x + i);
    float xx[4] = {xr.x, xr.y, xr.z, xr.w};
    float oo[4];
#pragma unroll
    for (int j = 0; j < 4; ++j) {
        int c = c0 + j;
        float mu  = sums[c] * (1.0f / N_VOX);
        float var = sums[64 + c] * (1.0f / N_VOX) - mu * mu;
        float rs  = rsqrtf(var + EPS_BN);
        float val = gamma[c] * (__bfloat162float(hv[j]) - mu) * rs + beta[c] + xx[j];
        oo[j] = fmaxf(val, 0.0f);
    }
    float4 ov = {oo[0], oo[1], oo[2], oo[3]};
    *(float4*)(out + i) = ov;
}

// ---------------- launcher ----------------

extern "C" void kernel_launch(void* const* d_in, const int* in_sizes, int n_in,
                              void* d_out, int out_size, void* d_ws, size_t ws_size,
                              hipStream_t stream) {
    const float* x      = (const float*)d_in[0];
    const float* W1     = (const float*)d_in[1];
    const float* gamma1 = (const float*)d_in[2];
    const float* beta1  = (const float*)d_in[3];
    const float* W2     = (const float*)d_in[4];
    const float* gamma2 = (const float*)d_in[5];
    const float* beta2  = (const float*)d_in[6];
    const int* in_maps  = (const int*)d_in[7];
    const int* out_maps = (const int*)d_in[8];
    float* out = (float*)d_out;

    char* ws = (char*)d_ws;
    size_t off = 0;
    auto alloc = [&](size_t bytes) -> void* {
        void* p = ws + off;
        off = (off + bytes + 255) & ~(size_t)255;
        return p;
    };
    int* nbrT           = (int*)alloc((size_t)27 * NP * 4);                    // 21.6 MB
    __hip_bfloat16* xb  = (__hip_bfloat16*)alloc((size_t)(N_VOX + 1) * 64 * 2); // 25.6 MB (reused as h1b)
    __hip_bfloat16* W1S = (__hip_bfloat16*)alloc((size_t)27 * 4096 * 2);
    __hip_bfloat16* W2S = (__hip_bfloat16*)alloc((size_t)27 * 4096 * 2);
    __hip_bfloat16* h   = (__hip_bfloat16*)alloc((size_t)N_VOX * 64 * 2);      // 25.6 MB
    float* sums         = (float*)alloc(256 * 4);
    __hip_bfloat16* h1b = xb;   // xb dead after conv1; reuse for BN1(relu) output

    const long elem_x = (long)(N_VOX + 1) * 64;

    fill_kernel   <<<dim3((NP / 4 + 255) / 256, 27), 256, 0, stream>>>(nbrT, sums);
    scatter_kernel<<<26 * 65536 / 256, 256, 0, stream>>>(out_maps, in_maps, nbrT);
    cast_x_kernel <<<(int)((elem_x / 4 + 255) / 256), 256, 0, stream>>>(x, xb);
    cast_w_kernel <<<(27 * 4096 + 255) / 256, 256, 0, stream>>>(W1, W2, W1S, W2S);

    conv_kernel   <<<NP / 256, 256, 0, stream>>>(xb, W1S, nbrT, h, sums);
    bnrelu_kernel <<<(int)((elem_x / 4 + 255) / 256), 256, 0, stream>>>(h, sums, gamma1, beta1, h1b);

    conv_kernel   <<<NP / 256, 256, 0, stream>>>(h1b, W2S, nbrT, h, sums + 128);
    final_kernel  <<<(int)(((long)N_VOX * 64 / 4 + 255) / 256), 256, 0, stream>>>(h, x, sums + 128, gamma2, beta2, out);
}